// Round 3
// baseline (2492.957 us; speedup 1.0000x reference)
//
#include <hip/hip_runtime.h>
#include <math.h>

#define N_ 64
#define C_ 64
#define T_ 512
#define V_ 25
#define S_ 3
#define I_ 16
#define TV_ (T_*V_)          // 12800
#define NCTV_ ((size_t)N_*C_*T_*V_)  // 52428800

// ---- workspace layout (float offsets) ----
#define WS_Y      0
#define WS_MT     52428800                  // N*C*T = 2097152
#define WS_ARAW   (WS_MT + 2097152)         // 120000 (dead after k_finishA; reused for Wd packs)
#define WS_AEFF   (WS_ARAW + 120000)        // 120000
#define WS_MS     (WS_AEFF + 120000)        // 102400
#define WS_FV     (WS_MS + 102400)          // 1600
#define WS_FT     (WS_FV + 1600)            // 32768
#define WS_FC     (WS_FT + 32768)           // 4096
#define WS_BNS    (WS_FC + 4096)            // 64
#define WS_BNQ    (WS_BNS + 64)             // 64
#define WS_TBNS   (WS_BNQ + 64)             // 64
#define WS_TBNQ   (WS_TBNS + 64)            // 64
#define WS_WT     (WS_TBNQ + 64)            // 36864 floats region; holds Apack (36864 ushort)

typedef __attribute__((ext_vector_type(8))) short bf16x8;
typedef __attribute__((ext_vector_type(4))) float f32x4;

__device__ inline ushort f2bf_rne(float x) {
  unsigned u = __float_as_uint(x);
  u = (u + 0x7FFFu + ((u >> 16) & 1u)) >> 16;
  return (ushort)u;
}

__device__ inline float bf2f(ushort h) {
  return __uint_as_float((unsigned)h << 16);
}

// split 4 fp32 into hi/lo bf16 pairs packed as uint2 (4 bf16 each)
__device__ inline void split4(const f32x4 d, uint2& h, uint2& l) {
  ushort h0 = f2bf_rne(d[0]), h1 = f2bf_rne(d[1]), h2 = f2bf_rne(d[2]), h3 = f2bf_rne(d[3]);
  ushort l0 = f2bf_rne(d[0] - bf2f(h0));
  ushort l1 = f2bf_rne(d[1] - bf2f(h1));
  ushort l2 = f2bf_rne(d[2] - bf2f(h2));
  ushort l3 = f2bf_rne(d[3] - bf2f(h3));
  h.x = (unsigned)h0 | ((unsigned)h1 << 16);
  h.y = (unsigned)h2 | ((unsigned)h3 << 16);
  l.x = (unsigned)l0 | ((unsigned)l1 << 16);
  l.y = (unsigned)l2 | ((unsigned)l3 << 16);
}

// ---------------- k_prepA: pack tcn_w into A-fragment order (bf16) ----------------
// Apack[((chunk*4 + wave)*64 + lane)*8 + jj] = bf16(w[o][c][kk])
//   chunk = kk*2 + cb ; o = wave*16 + (lane&15) ; c = cb*32 + (lane>>4)*8 + jj
__global__ void k_prepA(const float* __restrict__ tcnw, ushort* __restrict__ Apack) {
  int e = blockIdx.x*256 + threadIdx.x;
  if (e < 36864) {
    int jj = e & 7, lane = (e >> 3) & 63, wvv = (e >> 9) & 3, chunk = e >> 11;
    int kk = chunk >> 1, cb = chunk & 1;
    int o = wvv*16 + (lane & 15);
    int c = cb*32 + (lane >> 4)*8 + jj;
    Apack[e] = f2bf_rne(tcnw[(o*64 + c)*9 + kk]);
  }
}

// ---------------- k_prepW: pack Wd into A-fragment order, hi/lo bf16 split ----------------
// gc = s*2 + cb (6 K-chunks of 32 over k = s*64 + c)
// Wdh/Wdl[((gc*4 + wave)*64 + lane)*8 + jj] for o = wave*16+(lane&15), c = (gc&1)*32+(lane>>4)*8+jj
__global__ void k_prepW(const float* __restrict__ Wd, ushort* __restrict__ Wdh,
                        ushort* __restrict__ Wdl) {
  int e = blockIdx.x*256 + threadIdx.x;
  if (e < 12288) {
    int jj = e & 7, lane = (e >> 3) & 63, wvv = (e >> 9) & 3, gc = e >> 11;
    int o = wvv*16 + (lane & 15);
    int s = gc >> 1;
    int c = (gc & 1)*32 + (lane >> 4)*8 + jj;
    float w = Wd[((size_t)s*64 + o)*64 + c];
    ushort h = f2bf_rne(w);
    Wdh[e] = h;
    Wdl[e] = f2bf_rne(w - bf2f(h));
  }
}

// ---------------- k_gramm: MFMA Gram kernel ----------------
// Per block: n = blockIdx.y, 32-t chunk = blockIdx.x. 4 waves.
// For each s, for each 16-t sub-chunk:
//  stage1: fa/fb[i, j=(t16,v)] = W_{a,b}(16x64) . x(64x400) via MFMA (+bias),
//          written bf16 to LDS keyed [v][k = t16*16 + i] (KSTR=264).
//  stage2: Gram[v,w] += fa^T fb over K=256 via MFMA; wave = one 16x16 quadrant.
// End of s: atomicAdd into Araw[n,s,v,w]. Precision: single bf16 everywhere
// (error -> ~1e-5 in Araw, /8192 -> negligible in Aeff).
#define KSTR 264
__global__ __launch_bounds__(256) void k_gramm(
    const float* __restrict__ x, const float* __restrict__ Wa, const float* __restrict__ ba,
    const float* __restrict__ Wb, const float* __restrict__ bb, float* __restrict__ Araw) {
  const int tcb = blockIdx.x, n = blockIdx.y;
  const int tid = threadIdx.x;
  const int lane = tid & 63, wv = tid >> 6;
  const int l15 = lane & 15, l4 = lane >> 4;
  const int mt = wv >> 1, nt = wv & 1;
  __shared__ __align__(16) ushort faL[25*KSTR];   // 13200 B
  __shared__ __align__(16) ushort fbL[25*KSTR];   // 13200 B
  const float* xbase = x + (size_t)n*C_*TV_;

  for (int s = 0; s < S_; ++s) {
    // ---- W A-fragments (m=i=l15, k=c=cb*32+l4*8+jj) ----
    bf16x8 WaF[2], WbF[2];
    #pragma unroll
    for (int cb = 0; cb < 2; ++cb) {
      const float* wap = Wa + ((size_t)s*16 + l15)*64 + cb*32 + l4*8;
      const float* wbp = Wb + ((size_t)s*16 + l15)*64 + cb*32 + l4*8;
      bf16x8 va, vb;
      #pragma unroll
      for (int jj = 0; jj < 8; ++jj) {
        va[jj] = (short)f2bf_rne(wap[jj]);
        vb[jj] = (short)f2bf_rne(wbp[jj]);
      }
      WaF[cb] = va; WbF[cb] = vb;
    }
    const float4 baR = *(const float4*)&ba[s*16 + l4*4];
    const float4 bbR = *(const float4*)&bb[s*16 + l4*4];
    f32x4 gacc = (f32x4){0.f,0.f,0.f,0.f};

    for (int sub = 0; sub < 2; ++sub) {
      // ---- stage 1: 25 j-tiles of 16, round-robin across waves ----
      for (int tl = wv; tl < 25; tl += 4) {
        const int j = tl*16 + l15;                 // 0..399 within sub-chunk
        const int ts = j / 25, v = j - ts*25;
        const float* xp = xbase + (size_t)(l4*8)*TV_ + (tcb*800 + sub*400 + j);
        f32x4 fa_d = (f32x4){0.f,0.f,0.f,0.f};
        f32x4 fb_d = (f32x4){0.f,0.f,0.f,0.f};
        #pragma unroll
        for (int cb = 0; cb < 2; ++cb) {
          const float* xpc = xp + (size_t)cb*32*TV_;
          bf16x8 bfrag;
          #pragma unroll
          for (int jj = 0; jj < 8; ++jj) bfrag[jj] = (short)f2bf_rne(xpc[(size_t)jj*TV_]);
          fa_d = __builtin_amdgcn_mfma_f32_16x16x32_bf16(WaF[cb], bfrag, fa_d, 0, 0, 0);
          fb_d = __builtin_amdgcn_mfma_f32_16x16x32_bf16(WbF[cb], bfrag, fb_d, 0, 0, 0);
        }
        // bias + pack to bf16, write [v][ts*16 + i], i = l4*4 + r
        uint2 ha, hb;
        ha.x = (unsigned)f2bf_rne(fa_d[0] + baR.x) | ((unsigned)f2bf_rne(fa_d[1] + baR.y) << 16);
        ha.y = (unsigned)f2bf_rne(fa_d[2] + baR.z) | ((unsigned)f2bf_rne(fa_d[3] + baR.w) << 16);
        hb.x = (unsigned)f2bf_rne(fb_d[0] + bbR.x) | ((unsigned)f2bf_rne(fb_d[1] + bbR.y) << 16);
        hb.y = (unsigned)f2bf_rne(fb_d[2] + bbR.z) | ((unsigned)f2bf_rne(fb_d[3] + bbR.w) << 16);
        const int wo = v*KSTR + ts*16 + l4*4;
        *(uint2*)&faL[wo] = ha;
        *(uint2*)&fbL[wo] = hb;
      }
      __syncthreads();
      // ---- stage 2: Gram quadrant (mt,nt) per wave, K = 256 ----
      const int vr = mt*16 + l15;
      const int wc = nt*16 + l15;
      #pragma unroll
      for (int ch = 0; ch < 8; ++ch) {
        const int k0 = ch*32 + l4*8;
        bf16x8 af = (bf16x8){0,0,0,0,0,0,0,0};
        bf16x8 bf_ = (bf16x8){0,0,0,0,0,0,0,0};
        if (vr < 25) af  = *(const bf16x8*)&faL[vr*KSTR + k0];
        if (wc < 25) bf_ = *(const bf16x8*)&fbL[wc*KSTR + k0];
        gacc = __builtin_amdgcn_mfma_f32_16x16x32_bf16(af, bf_, gacc, 0, 0, 0);
      }
      __syncthreads();
    }
    // ---- flush this s's Gram quadrant ----
    float* dst = Araw + ((size_t)n*3 + s)*625;
    #pragma unroll
    for (int r = 0; r < 4; ++r) {
      const int vrow = mt*16 + l4*4 + r;
      const int wcol = nt*16 + l15;
      if (vrow < 25 && wcol < 25) atomicAdd(&dst[vrow*25 + wcol], gacc[r]);
    }
  }
}

// ---------------- k_finishA ----------------
__global__ void k_finishA(const float* __restrict__ Araw, const float* __restrict__ PA,
                          const float* __restrict__ alpha, float* __restrict__ Aeff) {
  int e = blockIdx.x*256 + threadIdx.x;
  if (e < 64*3*625) {
    int p = e % 625; int ns = e / 625; int s = ns % 3;
    Aeff[e] = PA[s*625 + p] + alpha[0] * tanhf(Araw[e] * (1.f/8192.f));
  }
}

// ---------------- k_gcnm: MFMA split-bf16 GCN ----------------
// Per block: n = blockIdx.y, 4 t-rows (100 j) = blockIdx.x (512/4 = 128 exact tiles).
// stage1: xa[s,c,j=(t,w)] = sum_v x[n,c,t,v]*Aeff[n,s,v,w] via MFMA
//   (A-op = X rows c, B-op = Aeff cols w), hi/lo split -> LDS B-fragment layout [j][c].
// stage2: y[o,j] += sum_c Wd[s,o,c]*xa[s,c,j] via MFMA, hi/lo 3-combo.
// epilogue: store y + fused BN1 stats.
// LDS = 2 x 112 x 72 x 2B = 32256 B -> 4 blocks/CU (VGPR ~115 caps at 4).
#define GSTR 72    // bf16 units per LDS row; 16B-aligned b128 frags
#define GROWS 112  // 100 valid j + 12 zero pad rows
#define GTL 4      // t-rows per block
__global__ __launch_bounds__(256, 4) void k_gcnm(
    const float* __restrict__ x, const float* __restrict__ Aeff,
    const ushort* __restrict__ Wdh, const ushort* __restrict__ Wdl,
    float* __restrict__ y, float* __restrict__ bns, float* __restrict__ bnq) {
  const int tb = blockIdx.x, n = blockIdx.y;
  const int t0 = tb*GTL;
  const int tid = threadIdx.x;
  const int lane = tid & 63, wv = tid >> 6;
  const int l15 = lane & 15, l4 = lane >> 4;
  const int crow = wv*16 + l15;         // stage-1 A-operand row (channel c)
  __shared__ __align__(16) ushort Bh[GROWS*GSTR];
  __shared__ __align__(16) ushort Bl[GROWS*GSTR];

  // zero the 12 pad rows (j_local 100..111) so stage2 never reads garbage
  for (int e = tid; e < 12*GSTR; e += 256) { Bh[100*GSTR + e] = 0; Bl[100*GSTR + e] = 0; }

  // ---- load X A-fragments once, hi/lo split (reused across s) ----
  bf16x8 Xh[GTL], Xl[GTL];
  #pragma unroll
  for (int tl = 0; tl < GTL; ++tl) {
    ushort xh[8], xl[8];
    #pragma unroll
    for (int jj = 0; jj < 8; ++jj) { xh[jj] = 0; xl[jj] = 0; }
    const int t = t0 + tl;              // always < 512 (128*4 grid exact)
    {
      const float* xp = x + ((size_t)(n*64 + crow)*T_ + t)*V_;
      if (l4 < 3) {
        #pragma unroll
        for (int jj = 0; jj < 8; ++jj) {
          float f = xp[l4*8 + jj];
          ushort h = f2bf_rne(f);
          xh[jj] = h;
          xl[jj] = f2bf_rne(f - bf2f(h));
        }
      } else {               // k-octet 24..31: only v=24 exists
        float f = xp[24];
        ushort h = f2bf_rne(f);
        xh[0] = h;
        xl[0] = f2bf_rne(f - bf2f(h));
      }
    }
    bf16x8 vh, vl;
    #pragma unroll
    for (int jj = 0; jj < 8; ++jj) { vh[jj] = (short)xh[jj]; vl[jj] = (short)xl[jj]; }
    Xh[tl] = vh; Xl[tl] = vl;
  }

  f32x4 acc[7];
  #pragma unroll
  for (int i = 0; i < 7; ++i) acc[i] = (f32x4){0.f,0.f,0.f,0.f};

  for (int s = 0; s < S_; ++s) {
    // ---- gather Aeff B-fragments (hi/lo), wt = 0,1 ----
    bf16x8 Ah[2], Al[2];
    #pragma unroll
    for (int wt = 0; wt < 2; ++wt) {
      const int w = wt*16 + l15;
      ushort ah[8], al[8];
      #pragma unroll
      for (int jj = 0; jj < 8; ++jj) { ah[jj] = 0; al[jj] = 0; }
      if (w < 25) {
        const float* ap = Aeff + ((size_t)n*3 + s)*625 + w;
        #pragma unroll
        for (int jj = 0; jj < 8; ++jj) {
          int v = l4*8 + jj;
          if (v < 25) {
            float f = ap[v*25];
            ushort h = f2bf_rne(f);
            ah[jj] = h;
            al[jj] = f2bf_rne(f - bf2f(h));
          }
        }
      }
      bf16x8 vh, vl;
      #pragma unroll
      for (int jj = 0; jj < 8; ++jj) { vh[jj] = (short)ah[jj]; vl[jj] = (short)al[jj]; }
      Ah[wt] = vh; Al[wt] = vl;
    }
    // ---- Wd A-fragments for this s's 2 K-chunks ----
    bf16x8 Wh[2], Wl[2];
    #pragma unroll
    for (int cc = 0; cc < 2; ++cc) {
      const size_t off = ((size_t)((s*2 + cc)*4 + wv)*64 + lane)*8;
      Wh[cc] = *(const bf16x8*)(Wdh + off);
      Wl[cc] = *(const bf16x8*)(Wdl + off);
    }
    __syncthreads();   // previous stage2 done reading Bs
    // ---- stage 1: xa = X @ Aeff_s, write hi/lo bf16 to LDS ----
    const int kloc = wv*16 + l4*4;
    #pragma unroll
    for (int tl = 0; tl < GTL; ++tl) {
      f32x4 d0 = (f32x4){0.f,0.f,0.f,0.f}, d1 = (f32x4){0.f,0.f,0.f,0.f};
      d0 = __builtin_amdgcn_mfma_f32_16x16x32_bf16(Xh[tl], Ah[0], d0, 0, 0, 0);
      d0 = __builtin_amdgcn_mfma_f32_16x16x32_bf16(Xh[tl], Al[0], d0, 0, 0, 0);
      d0 = __builtin_amdgcn_mfma_f32_16x16x32_bf16(Xl[tl], Ah[0], d0, 0, 0, 0);
      d1 = __builtin_amdgcn_mfma_f32_16x16x32_bf16(Xh[tl], Ah[1], d1, 0, 0, 0);
      d1 = __builtin_amdgcn_mfma_f32_16x16x32_bf16(Xh[tl], Al[1], d1, 0, 0, 0);
      d1 = __builtin_amdgcn_mfma_f32_16x16x32_bf16(Xl[tl], Ah[1], d1, 0, 0, 0);
      {
        uint2 hh, ll; split4(d0, hh, ll);
        const int j = tl*25 + l15;           // w = l15 < 16 < 25: always valid
        *(uint2*)&Bh[j*GSTR + kloc] = hh;
        *(uint2*)&Bl[j*GSTR + kloc] = ll;
      }
      if (l15 < 9) {                          // w = 16 + l15 < 25
        uint2 hh, ll; split4(d1, hh, ll);
        const int j = tl*25 + 16 + l15;
        *(uint2*)&Bh[j*GSTR + kloc] = hh;
        *(uint2*)&Bl[j*GSTR + kloc] = ll;
      }
    }
    __syncthreads();
    // ---- stage 2: acc += Wd_s @ xa_s (hi/lo 3-combo) ----
    #pragma unroll
    for (int cc = 0; cc < 2; ++cc) {
      #pragma unroll
      for (int jt2 = 0; jt2 < 7; ++jt2) {
        const int boff = (jt2*16 + l15)*GSTR + cc*32 + l4*8;
        bf16x8 bh = *(const bf16x8*)&Bh[boff];
        bf16x8 bl = *(const bf16x8*)&Bl[boff];
        acc[jt2] = __builtin_amdgcn_mfma_f32_16x16x32_bf16(Wh[cc], bh, acc[jt2], 0, 0, 0);
        acc[jt2] = __builtin_amdgcn_mfma_f32_16x16x32_bf16(Wh[cc], bl, acc[jt2], 0, 0, 0);
        acc[jt2] = __builtin_amdgcn_mfma_f32_16x16x32_bf16(Wl[cc], bh, acc[jt2], 0, 0, 0);
      }
    }
  }
  // ---- epilogue: store y + fused BN1 stats ----
  float so[4] = {0,0,0,0}, qo[4] = {0,0,0,0};
  const int obase = wv*16 + l4*4;
  #pragma unroll
  for (int jt2 = 0; jt2 < 7; ++jt2) {
    const int jl = jt2*16 + l15;
    const int j = tb*100 + jl;
    if (jl < 100) {
      #pragma unroll
      for (int r = 0; r < 4; ++r) {
        float val = acc[jt2][r];
        y[((size_t)n*64 + obase + r)*TV_ + j] = val;
        so[r] += val; qo[r] += val*val;
      }
    }
  }
  #pragma unroll
  for (int off = 1; off < 16; off <<= 1) {
    #pragma unroll
    for (int r = 0; r < 4; ++r) {
      so[r] += __shfl_xor(so[r], off);
      qo[r] += __shfl_xor(qo[r], off);
    }
  }
  if (l15 == 0) {
    #pragma unroll
    for (int r = 0; r < 4; ++r) {
      atomicAdd(&bns[obase + r], so[r]);
      atomicAdd(&bnq[obase + r], qo[r]);
    }
  }
}

// ---------------- k_bnapply ----------------
__global__ __launch_bounds__(256) void k_bnapply(
    float* __restrict__ y, const float* __restrict__ x,
    const float* __restrict__ bns, const float* __restrict__ bnq,
    const float* __restrict__ g, const float* __restrict__ b,
    float* __restrict__ Ms) {
  const int n = blockIdx.x, c = blockIdx.y;
  const float cnt = 1.f/819200.f;
  float m = bns[c]*cnt;
  float var = bnq[c]*cnt - m*m;
  float sc = g[c]*rsqrtf(var+1e-5f);
  float sh = b[c] - m*sc;
  const size_t off = ((size_t)n*64+c)*TV_;
  float* yb = y + off;
  const float* xb = x + off;
  const int v = threadIdx.x & 31, ts = threadIdx.x >> 5;
  float vs = 0.f;
  if (v < 25) {
    for (int t = ts; t < 512; t += 8) {
      int j = t*25+v;
      float val = fmaxf(sc*yb[j] + sh + xb[j], 0.f);
      yb[j] = val;
      vs += val;
    }
  }
  __shared__ float red[8][32];
  red[ts][v] = vs;
  __syncthreads();
  if (threadIdx.x < 32) {
    float t = 0.f;
    #pragma unroll
    for (int k=0;k<8;++k) t += red[k][threadIdx.x];
    if (threadIdx.x < 25) Ms[((size_t)n*64+c)*25 + threadIdx.x] = t;
  }
}

// ---------------- k_spat ----------------
__global__ void k_spat(const float* __restrict__ Ms, const float* __restrict__ saw,
                       const float* __restrict__ sab, float* __restrict__ fv) {
  const int n = blockIdx.x;
  const int v = threadIdx.x;
  if (v >= 25) return;
  float acc = sab[0];
  for (int c = 0; c < 64; ++c) {
    const float* mrow = Ms + ((size_t)n*64+c)*25;
    #pragma unroll
    for (int k = 0; k < 25; ++k) {
      int vv = v + k - 12;
      if (vv >= 0 && vv < 25) acc += saw[c*25+k] * mrow[vv] * (1.f/512.f);
    }
  }
  fv[n*25+v] = 1.f + 1.f/(1.f+expf(-acc));
}

// ---------------- k_tmean ----------------
__global__ __launch_bounds__(256) void k_tmean(const float* __restrict__ y,
    const float* __restrict__ fv, float* __restrict__ Mt) {
  const int n = blockIdx.x, c = blockIdx.y;
  __shared__ float fvs[32];
  if (threadIdx.x < 32) fvs[threadIdx.x] = (threadIdx.x<25)? fv[n*25+threadIdx.x] : 0.f;
  __syncthreads();
  const float* yb = y + ((size_t)n*64+c)*TV_;
  float* mb = Mt + ((size_t)n*64+c)*T_;
  const int v = threadIdx.x & 31;
  const int grp = threadIdx.x >> 5;
  float fvv = fvs[v];
  for (int t = grp; t < 512; t += 8) {
    float val = (v<25) ? yb[t*25+v]*fvv : 0.f;
    for (int off=16; off; off>>=1) val += __shfl_down(val, off, 32);
    if (v==0) mb[t] = val * (1.f/25.f);
  }
}

// ---------------- k_tconv ----------------
__global__ void k_tconv(const float* __restrict__ Mt, const float* __restrict__ taw,
                        const float* __restrict__ tab, float* __restrict__ ft) {
  const int n = blockIdx.x;
  __shared__ float w[64*9];
  for (int e = threadIdx.x; e < 576; e += 256) w[e] = taw[e];
  __syncthreads();
  for (int t = threadIdx.x; t < 512; t += 256) {
    float acc = tab[0];
    for (int c = 0; c < 64; ++c) {
      const float* mrow = Mt + ((size_t)n*64+c)*512;
      #pragma unroll
      for (int k = 0; k < 9; ++k) {
        int tt = t + k - 4;
        if (tt >= 0 && tt < 512) acc += w[c*9+k]*mrow[tt];
      }
    }
    ft[n*512+t] = 1.f + 1.f/(1.f+expf(-acc));
  }
}

// ---------------- k_chan ----------------
__global__ void k_chan(const float* __restrict__ Mt, const float* __restrict__ ft,
    const float* __restrict__ f1w, const float* __restrict__ f1b,
    const float* __restrict__ f2w, const float* __restrict__ f2b,
    float* __restrict__ fc) {
  const int n = blockIdx.x;
  const int c = threadIdx.x;
  __shared__ float m3[64], h[32];
  float acc = 0.f;
  const float* mrow = Mt + ((size_t)n*64+c)*512;
  const float* fr = ft + n*512;
  for (int t = 0; t < 512; ++t) acc += mrow[t]*fr[t];
  m3[c] = acc * (1.f/512.f);
  __syncthreads();
  if (c < 32) {
    float a = f1b[c];
    for (int j = 0; j < 64; ++j) a += f1w[c*64+j]*m3[j];
    h[c] = fmaxf(a, 0.f);
  }
  __syncthreads();
  float a = f2b[c];
  for (int j = 0; j < 32; ++j) a += f2w[c*32+j]*h[j];
  fc[n*64+c] = 1.f + 1.f/(1.f+expf(-a));
}

// ---------------- k_tcnm: MFMA bf16 TCN ----------------
// z[n][o][j] = sum_{c,kk} w[o][c][kk] * ytil[n][c][j+(kk-4)*25],  j = t*25+v
// ytil = y1 * fc[c] * ft[t] * fv[v], zero-padded in t.
// grid (100 j-tiles of 128, N), 256 threads = 4 waves; wave w -> o-tile w*16.
// LDS ~49.7 KB -> 3 blocks/CU.
#define BROW 328
#define BSTR 72        // bf16 units; conflict-free for b128 writes and frag reads
__global__ __launch_bounds__(256) void k_tcnm(
    const float* __restrict__ y, const float* __restrict__ fv,
    const float* __restrict__ ft, const float* __restrict__ fc,
    const ushort* __restrict__ Apack, float* __restrict__ out,
    float* __restrict__ tbns, float* __restrict__ tbnq) {
  const int jt = blockIdx.x, n = blockIdx.y;
  const int j0 = jt*128;
  const int tid = threadIdx.x;
  const int lane = tid & 63, wv = tid >> 6;
  __shared__ __align__(16) ushort Bs[BROW*BSTR];   // 47232 B
  __shared__ float fts[512], fvs[32], fcs[64];
  for (int e = tid; e < 512; e += 256) fts[e] = ft[n*512+e];
  if (tid < 32) fvs[tid] = (tid < 25) ? fv[n*25+tid] : 0.f;
  if (tid >= 64 && tid < 128) fcs[tid-64] = fc[n*64 + tid-64];
  __syncthreads();
  // ---- stage Bs[j][c] = bf16(ytil), j in [j0-100, j0+228) ----
  const float* yb = y + (size_t)n*64*TV_;
  for (int item = wv; item < 48; item += 4) {     // item = jc*8 + ce ; jc < 6
    int jc = item >> 3, ce = item & 7;
    int j = jc*64 + lane;
    if (j < BROW) {
      int jg = j0 - 100 + j;
      unsigned p0=0,p1=0,p2=0,p3=0;
      if (jg >= 0 && jg < TV_) {
        int t = jg / 25, v = jg - t*25;
        float f = fts[t]*fvs[v];
        ushort pk[8];
        #pragma unroll
        for (int r = 0; r < 8; ++r) {
          int c = ce*8 + r;
          pk[r] = f2bf_rne(yb[(size_t)c*TV_ + jg] * f * fcs[c]);
        }
        p0 = (unsigned)pk[0] | ((unsigned)pk[1]<<16);
        p1 = (unsigned)pk[2] | ((unsigned)pk[3]<<16);
        p2 = (unsigned)pk[4] | ((unsigned)pk[5]<<16);
        p3 = (unsigned)pk[6] | ((unsigned)pk[7]<<16);
      }
      uint4 w4; w4.x=p0; w4.y=p1; w4.z=p2; w4.w=p3;
      *(uint4*)&Bs[j*BSTR + ce*8] = w4;
    }
  }
  __syncthreads();
  // ---- MFMA K-loop: 18 chunks of K=32 (kk outer, c-half inner) ----
  const int l15 = lane & 15, l4 = lane >> 4;
  f32x4 acc[8];
  #pragma unroll
  for (int i = 0; i < 8; ++i) acc[i] = (f32x4){0.f,0.f,0.f,0.f};
  for (int kk = 0; kk < 9; ++kk) {
    #pragma unroll
    for (int cb = 0; cb < 2; ++cb) {
      const int chunk = kk*2 + cb;
      bf16x8 afrag = *(const bf16x8*)(Apack + (size_t)((chunk*4 + wv)*64 + lane)*8);
      const int rbase = kk*25 + l15;
      const int ccol = cb*32 + l4*8;
      #pragma unroll
      for (int jt2 = 0; jt2 < 8; ++jt2) {
        bf16x8 bfrag = *(const bf16x8*)&Bs[(rbase + jt2*16)*BSTR + ccol];
        acc[jt2] = __builtin_amdgcn_mfma_f32_16x16x32_bf16(afrag, bfrag, acc[jt2], 0, 0, 0);
      }
    }
  }
  // ---- epilogue: store z + BN2 stats ----
  float so[4] = {0,0,0,0}, qo[4] = {0,0,0,0};
  const int obase = wv*16 + l4*4;
  #pragma unroll
  for (int jt2 = 0; jt2 < 8; ++jt2) {
    const int j = j0 + jt2*16 + l15;
    #pragma unroll
    for (int r = 0; r < 4; ++r) {
      float val = acc[jt2][r];
      out[((size_t)n*64 + obase + r)*TV_ + j] = val;
      so[r] += val; qo[r] += val*val;
    }
  }
  #pragma unroll
  for (int off = 1; off < 16; off <<= 1) {
    #pragma unroll
    for (int r = 0; r < 4; ++r) {
      so[r] += __shfl_xor(so[r], off);
      qo[r] += __shfl_xor(qo[r], off);
    }
  }
  if (l15 == 0) {
    #pragma unroll
    for (int r = 0; r < 4; ++r) {
      atomicAdd(&tbns[obase + r], so[r]);
      atomicAdd(&tbnq[obase + r], qo[r]);
    }
  }
}

// ---------------- k_final ----------------
__global__ void k_final(float* __restrict__ z, const float* __restrict__ x,
    const float* __restrict__ tbns, const float* __restrict__ tbnq,
    const float* __restrict__ tg, const float* __restrict__ tb) {
  size_t e = (size_t)blockIdx.x*256 + threadIdx.x;
  if (e < NCTV_/4) {
    int c = (int)((e / 3200) & 63);
    const float cnt = 1.f/819200.f;
    float m = tbns[c]*cnt;
    float var = tbnq[c]*cnt - m*m;
    float sc = tg[c]*rsqrtf(var+1e-5f);
    float sh = tb[c] - m*sc;
    float4 zv = ((float4*)z)[e];
    float4 xv = ((const float4*)x)[e];
    float4 o;
    o.x = fmaxf(sc*zv.x+sh+xv.x, 0.f);
    o.y = fmaxf(sc*zv.y+sh+xv.y, 0.f);
    o.z = fmaxf(sc*zv.z+sh+xv.z, 0.f);
    o.w = fmaxf(sc*zv.w+sh+xv.w, 0.f);
    ((float4*)z)[e] = o;
  }
}

extern "C" void kernel_launch(void* const* d_in, const int* in_sizes, int n_in,
                              void* d_out, int out_size, void* d_ws, size_t ws_size,
                              hipStream_t stream) {
  (void)in_sizes; (void)n_in; (void)out_size; (void)ws_size;
  const float* x    = (const float*)d_in[0];
  const float* PA   = (const float*)d_in[1];
  const float* alpha= (const float*)d_in[2];
  const float* Wa   = (const float*)d_in[3];
  const float* ba   = (const float*)d_in[4];
  const float* Wb   = (const float*)d_in[5];
  const float* bb   = (const float*)d_in[6];
  const float* Wd   = (const float*)d_in[7];
  // d_in[8] = bd : cancels exactly in training-mode BN1
  const float* bng  = (const float*)d_in[9];
  const float* bnb  = (const float*)d_in[10];
  const float* saw  = (const float*)d_in[11];
  const float* sab  = (const float*)d_in[12];
  const float* taw  = (const float*)d_in[13];
  const float* tab  = (const float*)d_in[14];
  const float* f1w  = (const float*)d_in[15];
  const float* f1b  = (const float*)d_in[16];
  const float* f2w  = (const float*)d_in[17];
  const float* f2b  = (const float*)d_in[18];
  const float* tcnw = (const float*)d_in[19];
  // d_in[20] = tcn_b : cancels exactly in training-mode BN2
  const float* tbg  = (const float*)d_in[21];
  const float* tbb  = (const float*)d_in[22];

  float* ws = (float*)d_ws;
  float* out = (float*)d_out;
  float* y    = ws + WS_Y;
  float* Mt   = ws + WS_MT;
  float* Araw = ws + WS_ARAW;
  float* Aeff = ws + WS_AEFF;
  float* Ms   = ws + WS_MS;
  float* fv   = ws + WS_FV;
  float* ft   = ws + WS_FT;
  float* fc   = ws + WS_FC;
  float* bns  = ws + WS_BNS;
  float* bnq  = ws + WS_BNQ;
  float* tbns = ws + WS_TBNS;
  float* tbnq = ws + WS_TBNQ;
  ushort* Apack = (ushort*)(ws + WS_WT);
  // Wd hi/lo packs live in the Araw region (dead after k_finishA; rewritten every iteration)
  ushort* Wdh = (ushort*)(ws + WS_ARAW);
  ushort* Wdl = Wdh + 12288;

  hipMemsetAsync(Araw, 0, 120000*sizeof(float), stream);
  hipMemsetAsync(bns, 0, 256*sizeof(float), stream);   // bns,bnq,tbns,tbnq contiguous

  k_prepA<<<144, 256, 0, stream>>>(tcnw, Apack);
  k_gramm<<<dim3(16,64), 256, 0, stream>>>(x, Wa, ba, Wb, bb, Araw);
  k_finishA<<<469, 256, 0, stream>>>(Araw, PA, alpha, Aeff);
  k_prepW<<<48, 256, 0, stream>>>(Wd, Wdh, Wdl);       // overwrites Araw (now dead)
  k_gcnm<<<dim3(128,64), 256, 0, stream>>>(x, Aeff, Wdh, Wdl, y, bns, bnq);
  k_bnapply<<<dim3(64,64), 256, 0, stream>>>(y, x, bns, bnq, bng, bnb, Ms);
  k_spat<<<64, 64, 0, stream>>>(Ms, saw, sab, fv);
  k_tmean<<<dim3(64,64), 256, 0, stream>>>(y, fv, Mt);
  k_tconv<<<64, 256, 0, stream>>>(Mt, taw, tab, ft);
  k_chan<<<64, 64, 0, stream>>>(Mt, ft, f1w, f1b, f2w, f2b, fc);
  k_tcnm<<<dim3(100,64), 256, 0, stream>>>(y, fv, ft, fc, Apack, out, tbns, tbnq);
  k_final<<<51200, 256, 0, stream>>>(out, x, tbns, tbnq, tbg, tbb);
}

// Round 6
// 1757.717 us; speedup vs baseline: 1.4183x; 1.4183x over previous
//
#include <hip/hip_runtime.h>
#include <math.h>

#define N_ 64
#define C_ 64
#define T_ 512
#define V_ 25
#define S_ 3
#define I_ 16
#define TV_ (T_*V_)          // 12800
#define NCTV_ ((size_t)N_*C_*T_*V_)  // 52428800

// ---- workspace layout (float offsets) ----
#define WS_Y      0
#define WS_MT     52428800                  // N*C*T = 2097152 (Fpack lives here pre-k_tmean)
#define WS_ARAW   (WS_MT + 2097152)         // 120000 (dead after k_finishA; reused for Wd packs)
#define WS_AEFF   (WS_ARAW + 120000)        // 120000
#define WS_MS     (WS_AEFF + 120000)        // 102400
#define WS_FV     (WS_MS + 102400)          // 1600
#define WS_FT     (WS_FV + 1600)            // 32768
#define WS_FC     (WS_FT + 32768)           // 4096
#define WS_BNS    (WS_FC + 4096)            // 64
#define WS_BNQ    (WS_BNS + 64)             // 64
#define WS_TBNS   (WS_BNQ + 64)             // 64
#define WS_TBNQ   (WS_TBNS + 64)            // 64
#define WS_WT     (WS_TBNQ + 64)            // 36864 floats region; holds Apack (36864 ushort)

#define FPK_HALF 196608   // ushorts in the hi half of Fpack (lo half follows)

typedef __attribute__((ext_vector_type(8))) short bf16x8;
typedef __attribute__((ext_vector_type(4))) float f32x4;

__device__ inline ushort f2bf_rne(float x) {
  unsigned u = __float_as_uint(x);
  u = (u + 0x7FFFu + ((u >> 16) & 1u)) >> 16;
  return (ushort)u;
}

__device__ inline float bf2f(ushort h) {
  return __uint_as_float((unsigned)h << 16);
}

// split 4 fp32 into hi/lo bf16 pairs packed as uint2 (4 bf16 each)
__device__ inline void split4(const f32x4 d, uint2& h, uint2& l) {
  ushort h0 = f2bf_rne(d[0]), h1 = f2bf_rne(d[1]), h2 = f2bf_rne(d[2]), h3 = f2bf_rne(d[3]);
  ushort l0 = f2bf_rne(d[0] - bf2f(h0));
  ushort l1 = f2bf_rne(d[1] - bf2f(h1));
  ushort l2 = f2bf_rne(d[2] - bf2f(h2));
  ushort l3 = f2bf_rne(d[3] - bf2f(h3));
  h.x = (unsigned)h0 | ((unsigned)h1 << 16);
  h.y = (unsigned)h2 | ((unsigned)h3 << 16);
  l.x = (unsigned)l0 | ((unsigned)l1 << 16);
  l.y = (unsigned)l2 | ((unsigned)l3 << 16);
}

// ---------------- k_prepA: pack tcn_w into A-fragment order (bf16) ----------------
// Apack[((chunk*4 + wave)*64 + lane)*8 + jj] = bf16(w[o][c][kk])
//   chunk = kk*2 + cb ; o = wave*16 + (lane&15) ; c = cb*32 + (lane>>4)*8 + jj
__global__ void k_prepA(const float* __restrict__ tcnw, ushort* __restrict__ Apack) {
  int e = blockIdx.x*256 + threadIdx.x;
  if (e < 36864) {
    int jj = e & 7, lane = (e >> 3) & 63, wvv = (e >> 9) & 3, chunk = e >> 11;
    int kk = chunk >> 1, cb = chunk & 1;
    int o = wvv*16 + (lane & 15);
    int c = cb*32 + (lane >> 4)*8 + jj;
    Apack[e] = f2bf_rne(tcnw[(o*64 + c)*9 + kk]);
  }
}

// ---------------- k_prepW: pack Wd into A-fragment order, hi/lo bf16 split ----------------
// gc = s*2 + cb (6 K-chunks of 32 over k = s*64 + c)
// Wdh/Wdl[((gc*4 + wave)*64 + lane)*8 + jj] for o = wave*16+(lane&15), c = (gc&1)*32+(lane>>4)*8+jj
__global__ void k_prepW(const float* __restrict__ Wd, ushort* __restrict__ Wdh,
                        ushort* __restrict__ Wdl) {
  int e = blockIdx.x*256 + threadIdx.x;
  if (e < 12288) {
    int jj = e & 7, lane = (e >> 3) & 63, wvv = (e >> 9) & 3, gc = e >> 11;
    int o = wvv*16 + (lane & 15);
    int s = gc >> 1;
    int c = (gc & 1)*32 + (lane >> 4)*8 + jj;
    float w = Wd[((size_t)s*64 + o)*64 + c];
    ushort h = f2bf_rne(w);
    Wdh[e] = h;
    Wdl[e] = f2bf_rne(w - bf2f(h));
  }
}

// ---------------- k_prepF: pack Aeff into hi/lo B-fragments ----------------
// For (n,s,wt): B-fragment col w = wt*16 + (lane&15), k = v = (lane>>4)*8 + jj.
// Fh[(((n*3+s)*2+wt)*64+lane)*8+jj] = bf16_hi(Aeff[n,s,v,w]) (0 outside 25x25);
// Fl at +FPK_HALF. Single coalesced b128 load per fragment in k_gcnm.
__global__ void k_prepF(const float* __restrict__ Aeff, ushort* __restrict__ Fpk) {
  int e = blockIdx.x*256 + threadIdx.x;   // 196608 total
  int jj = e & 7, lane = (e >> 3) & 63, wt = (e >> 9) & 1, rest = e >> 10; // rest = n*3+s
  int w = wt*16 + (lane & 15);
  int v = (lane >> 4)*8 + jj;
  float f = 0.f;
  if (w < 25 && v < 25) f = Aeff[(size_t)rest*625 + v*25 + w];
  ushort h = f2bf_rne(f);
  Fpk[e] = h;
  Fpk[FPK_HALF + e] = f2bf_rne(f - bf2f(h));
}

// ---------------- k_gramm: MFMA Gram kernel ----------------
#define KSTR 264
__global__ __launch_bounds__(256) void k_gramm(
    const float* __restrict__ x, const float* __restrict__ Wa, const float* __restrict__ ba,
    const float* __restrict__ Wb, const float* __restrict__ bb, float* __restrict__ Araw) {
  const int tcb = blockIdx.x, n = blockIdx.y;
  const int tid = threadIdx.x;
  const int lane = tid & 63, wv = tid >> 6;
  const int l15 = lane & 15, l4 = lane >> 4;
  const int mt = wv >> 1, nt = wv & 1;
  __shared__ __align__(16) ushort faL[25*KSTR];   // 13200 B
  __shared__ __align__(16) ushort fbL[25*KSTR];   // 13200 B
  const float* xbase = x + (size_t)n*C_*TV_;

  for (int s = 0; s < S_; ++s) {
    bf16x8 WaF[2], WbF[2];
    #pragma unroll
    for (int cb = 0; cb < 2; ++cb) {
      const float* wap = Wa + ((size_t)s*16 + l15)*64 + cb*32 + l4*8;
      const float* wbp = Wb + ((size_t)s*16 + l15)*64 + cb*32 + l4*8;
      bf16x8 va, vb;
      #pragma unroll
      for (int jj = 0; jj < 8; ++jj) {
        va[jj] = (short)f2bf_rne(wap[jj]);
        vb[jj] = (short)f2bf_rne(wbp[jj]);
      }
      WaF[cb] = va; WbF[cb] = vb;
    }
    const float4 baR = *(const float4*)&ba[s*16 + l4*4];
    const float4 bbR = *(const float4*)&bb[s*16 + l4*4];
    f32x4 gacc = (f32x4){0.f,0.f,0.f,0.f};

    for (int sub = 0; sub < 2; ++sub) {
      for (int tl = wv; tl < 25; tl += 4) {
        const int j = tl*16 + l15;
        const int ts = j / 25, v = j - ts*25;
        const float* xp = xbase + (size_t)(l4*8)*TV_ + (tcb*800 + sub*400 + j);
        f32x4 fa_d = (f32x4){0.f,0.f,0.f,0.f};
        f32x4 fb_d = (f32x4){0.f,0.f,0.f,0.f};
        #pragma unroll
        for (int cb = 0; cb < 2; ++cb) {
          const float* xpc = xp + (size_t)cb*32*TV_;
          bf16x8 bfrag;
          #pragma unroll
          for (int jj = 0; jj < 8; ++jj) bfrag[jj] = (short)f2bf_rne(xpc[(size_t)jj*TV_]);
          fa_d = __builtin_amdgcn_mfma_f32_16x16x32_bf16(WaF[cb], bfrag, fa_d, 0, 0, 0);
          fb_d = __builtin_amdgcn_mfma_f32_16x16x32_bf16(WbF[cb], bfrag, fb_d, 0, 0, 0);
        }
        uint2 ha, hb;
        ha.x = (unsigned)f2bf_rne(fa_d[0] + baR.x) | ((unsigned)f2bf_rne(fa_d[1] + baR.y) << 16);
        ha.y = (unsigned)f2bf_rne(fa_d[2] + baR.z) | ((unsigned)f2bf_rne(fa_d[3] + baR.w) << 16);
        hb.x = (unsigned)f2bf_rne(fb_d[0] + bbR.x) | ((unsigned)f2bf_rne(fb_d[1] + bbR.y) << 16);
        hb.y = (unsigned)f2bf_rne(fb_d[2] + bbR.z) | ((unsigned)f2bf_rne(fb_d[3] + bbR.w) << 16);
        const int wo = v*KSTR + ts*16 + l4*4;
        *(uint2*)&faL[wo] = ha;
        *(uint2*)&fbL[wo] = hb;
      }
      __syncthreads();
      const int vr = mt*16 + l15;
      const int wc = nt*16 + l15;
      #pragma unroll
      for (int ch = 0; ch < 8; ++ch) {
        const int k0 = ch*32 + l4*8;
        bf16x8 af = (bf16x8){0,0,0,0,0,0,0,0};
        bf16x8 bf_ = (bf16x8){0,0,0,0,0,0,0,0};
        if (vr < 25) af  = *(const bf16x8*)&faL[vr*KSTR + k0];
        if (wc < 25) bf_ = *(const bf16x8*)&fbL[wc*KSTR + k0];
        gacc = __builtin_amdgcn_mfma_f32_16x16x32_bf16(af, bf_, gacc, 0, 0, 0);
      }
      __syncthreads();
    }
    float* dst = Araw + ((size_t)n*3 + s)*625;
    #pragma unroll
    for (int r = 0; r < 4; ++r) {
      const int vrow = mt*16 + l4*4 + r;
      const int wcol = nt*16 + l15;
      if (vrow < 25 && wcol < 25) atomicAdd(&dst[vrow*25 + wcol], gacc[r]);
    }
  }
}

// ---------------- k_finishA ----------------
__global__ void k_finishA(const float* __restrict__ Araw, const float* __restrict__ PA,
                          const float* __restrict__ alpha, float* __restrict__ Aeff) {
  int e = blockIdx.x*256 + threadIdx.x;
  if (e < 64*3*625) {
    int p = e % 625; int ns = e / 625; int s = ns % 3;
    Aeff[e] = PA[s*625 + p] + alpha[0] * tanhf(Araw[e] * (1.f/8192.f));
  }
}

// ---------------- k_gcnm: MFMA split-bf16 GCN (R2-verified structure) ----------------
// Per block: n = blockIdx.y, 10 t-rows (250 j) = blockIdx.x.
// stage1: xa = X @ Aeff_s via MFMA (Aeff frags pre-packed by k_prepF -> 1 b128 load each),
//   hi/lo split -> LDS B-fragment layout [j][c].
// stage2: y += Wd_s @ xa via MFMA, hi/lo 3-combo. Epilogue: store y + fused BN1 stats.
#define GSTR 72
__global__ __launch_bounds__(256, 2) void k_gcnm(
    const float* __restrict__ x, const ushort* __restrict__ Fpk,
    const ushort* __restrict__ Wdh, const ushort* __restrict__ Wdl,
    float* __restrict__ y, float* __restrict__ bns, float* __restrict__ bnq) {
  const int tb = blockIdx.x, n = blockIdx.y;
  const int t0 = tb*10;
  const int tid = threadIdx.x;
  const int lane = tid & 63, wv = tid >> 6;
  const int l15 = lane & 15, l4 = lane >> 4;
  const int crow = wv*16 + l15;         // stage-1 A-operand row (channel c)
  __shared__ __align__(16) ushort Bh[256*GSTR];   // 36864 B
  __shared__ __align__(16) ushort Bl[256*GSTR];   // 36864 B

  // zero the 6 pad rows (j_local 250..255) so stage2 never reads garbage
  for (int e = tid; e < 6*GSTR; e += 256) { Bh[250*GSTR + e] = 0; Bl[250*GSTR + e] = 0; }

  // ---- load X A-fragments once, hi/lo split (reused across s) ----
  bf16x8 Xh[10], Xl[10];
  #pragma unroll
  for (int tl = 0; tl < 10; ++tl) {
    ushort xh[8], xl[8];
    #pragma unroll
    for (int jj = 0; jj < 8; ++jj) { xh[jj] = 0; xl[jj] = 0; }
    const int t = t0 + tl;
    if (t < T_) {
      const float* xp = x + ((size_t)(n*64 + crow)*T_ + t)*V_;
      if (l4 < 3) {
        #pragma unroll
        for (int jj = 0; jj < 8; ++jj) {
          float f = xp[l4*8 + jj];
          ushort h = f2bf_rne(f);
          xh[jj] = h;
          xl[jj] = f2bf_rne(f - bf2f(h));
        }
      } else {               // k-octet 24..31: only v=24 exists
        float f = xp[24];
        ushort h = f2bf_rne(f);
        xh[0] = h;
        xl[0] = f2bf_rne(f - bf2f(h));
      }
    }
    bf16x8 vh, vl;
    #pragma unroll
    for (int jj = 0; jj < 8; ++jj) { vh[jj] = (short)xh[jj]; vl[jj] = (short)xl[jj]; }
    Xh[tl] = vh; Xl[tl] = vl;
  }

  f32x4 acc[16];
  #pragma unroll
  for (int i = 0; i < 16; ++i) acc[i] = (f32x4){0.f,0.f,0.f,0.f};

  for (int s = 0; s < S_; ++s) {
    // ---- Aeff B-fragments (hi/lo): pre-packed, 4 coalesced b128 loads ----
    bf16x8 Ah[2], Al[2];
    {
      const size_t fb = ((size_t)((n*3 + s)*2)*64 + lane)*8;
      Ah[0] = *(const bf16x8*)(Fpk + fb);
      Ah[1] = *(const bf16x8*)(Fpk + fb + 512);
      Al[0] = *(const bf16x8*)(Fpk + FPK_HALF + fb);
      Al[1] = *(const bf16x8*)(Fpk + FPK_HALF + fb + 512);
    }
    // ---- Wd A-fragments for this s's 2 K-chunks ----
    bf16x8 Wh[2], Wl[2];
    #pragma unroll
    for (int cc = 0; cc < 2; ++cc) {
      const size_t off = ((size_t)((s*2 + cc)*4 + wv)*64 + lane)*8;
      Wh[cc] = *(const bf16x8*)(Wdh + off);
      Wl[cc] = *(const bf16x8*)(Wdl + off);
    }
    __syncthreads();   // previous stage2 done reading Bs
    // ---- stage 1: xa = X @ Aeff_s, write hi/lo bf16 to LDS ----
    const int kloc = wv*16 + l4*4;
    #pragma unroll
    for (int tl = 0; tl < 10; ++tl) {
      f32x4 d0 = (f32x4){0.f,0.f,0.f,0.f}, d1 = (f32x4){0.f,0.f,0.f,0.f};
      d0 = __builtin_amdgcn_mfma_f32_16x16x32_bf16(Xh[tl], Ah[0], d0, 0, 0, 0);
      d0 = __builtin_amdgcn_mfma_f32_16x16x32_bf16(Xh[tl], Al[0], d0, 0, 0, 0);
      d0 = __builtin_amdgcn_mfma_f32_16x16x32_bf16(Xl[tl], Ah[0], d0, 0, 0, 0);
      d1 = __builtin_amdgcn_mfma_f32_16x16x32_bf16(Xh[tl], Ah[1], d1, 0, 0, 0);
      d1 = __builtin_amdgcn_mfma_f32_16x16x32_bf16(Xh[tl], Al[1], d1, 0, 0, 0);
      d1 = __builtin_amdgcn_mfma_f32_16x16x32_bf16(Xl[tl], Ah[1], d1, 0, 0, 0);
      {
        uint2 hh, ll; split4(d0, hh, ll);
        const int j = tl*25 + l15;           // w = l15 < 16 < 25: always valid
        *(uint2*)&Bh[j*GSTR + kloc] = hh;
        *(uint2*)&Bl[j*GSTR + kloc] = ll;
      }
      if (l15 < 9) {                          // w = 16 + l15 < 25
        uint2 hh, ll; split4(d1, hh, ll);
        const int j = tl*25 + 16 + l15;
        *(uint2*)&Bh[j*GSTR + kloc] = hh;
        *(uint2*)&Bl[j*GSTR + kloc] = ll;
      }
    }
    __syncthreads();
    // ---- stage 2: acc += Wd_s @ xa_s (hi/lo 3-combo) ----
    #pragma unroll
    for (int cc = 0; cc < 2; ++cc) {
      #pragma unroll
      for (int jt2 = 0; jt2 < 16; ++jt2) {
        const int boff = (jt2*16 + l15)*GSTR + cc*32 + l4*8;
        bf16x8 bh = *(const bf16x8*)&Bh[boff];
        bf16x8 bl = *(const bf16x8*)&Bl[boff];
        acc[jt2] = __builtin_amdgcn_mfma_f32_16x16x32_bf16(Wh[cc], bh, acc[jt2], 0, 0, 0);
        acc[jt2] = __builtin_amdgcn_mfma_f32_16x16x32_bf16(Wh[cc], bl, acc[jt2], 0, 0, 0);
        acc[jt2] = __builtin_amdgcn_mfma_f32_16x16x32_bf16(Wl[cc], bh, acc[jt2], 0, 0, 0);
      }
    }
  }
  // ---- epilogue: store y + fused BN1 stats ----
  float so[4] = {0,0,0,0}, qo[4] = {0,0,0,0};
  const int obase = wv*16 + l4*4;
  #pragma unroll
  for (int jt2 = 0; jt2 < 16; ++jt2) {
    const int jl = jt2*16 + l15;
    const int j = tb*250 + jl;
    if (jl < 250 && j < TV_) {
      #pragma unroll
      for (int r = 0; r < 4; ++r) {
        float val = acc[jt2][r];
        y[((size_t)n*64 + obase + r)*TV_ + j] = val;
        so[r] += val; qo[r] += val*val;
      }
    }
  }
  #pragma unroll
  for (int off = 1; off < 16; off <<= 1) {
    #pragma unroll
    for (int r = 0; r < 4; ++r) {
      so[r] += __shfl_xor(so[r], off);
      qo[r] += __shfl_xor(qo[r], off);
    }
  }
  if (l15 == 0) {
    #pragma unroll
    for (int r = 0; r < 4; ++r) {
      atomicAdd(&bns[obase + r], so[r]);
      atomicAdd(&bnq[obase + r], qo[r]);
    }
  }
}

// ---------------- k_bnapply ----------------
__global__ __launch_bounds__(256) void k_bnapply(
    float* __restrict__ y, const float* __restrict__ x,
    const float* __restrict__ bns, const float* __restrict__ bnq,
    const float* __restrict__ g, const float* __restrict__ b,
    float* __restrict__ Ms) {
  const int n = blockIdx.x, c = blockIdx.y;
  const float cnt = 1.f/819200.f;
  float m = bns[c]*cnt;
  float var = bnq[c]*cnt - m*m;
  float sc = g[c]*rsqrtf(var+1e-5f);
  float sh = b[c] - m*sc;
  const size_t off = ((size_t)n*64+c)*TV_;
  float* yb = y + off;
  const float* xb = x + off;
  const int v = threadIdx.x & 31, ts = threadIdx.x >> 5;
  float vs = 0.f;
  if (v < 25) {
    for (int t = ts; t < 512; t += 8) {
      int j = t*25+v;
      float val = fmaxf(sc*yb[j] + sh + xb[j], 0.f);
      yb[j] = val;
      vs += val;
    }
  }
  __shared__ float red[8][32];
  red[ts][v] = vs;
  __syncthreads();
  if (threadIdx.x < 32) {
    float t = 0.f;
    #pragma unroll
    for (int k=0;k<8;++k) t += red[k][threadIdx.x];
    if (threadIdx.x < 25) Ms[((size_t)n*64+c)*25 + threadIdx.x] = t;
  }
}

// ---------------- k_spat ----------------
__global__ void k_spat(const float* __restrict__ Ms, const float* __restrict__ saw,
                       const float* __restrict__ sab, float* __restrict__ fv) {
  const int n = blockIdx.x;
  const int v = threadIdx.x;
  if (v >= 25) return;
  float acc = sab[0];
  for (int c = 0; c < 64; ++c) {
    const float* mrow = Ms + ((size_t)n*64+c)*25;
    #pragma unroll
    for (int k = 0; k < 25; ++k) {
      int vv = v + k - 12;
      if (vv >= 0 && vv < 25) acc += saw[c*25+k] * mrow[vv] * (1.f/512.f);
    }
  }
  fv[n*25+v] = 1.f + 1.f/(1.f+expf(-acc));
}

// ---------------- k_tmean ----------------
__global__ __launch_bounds__(256) void k_tmean(const float* __restrict__ y,
    const float* __restrict__ fv, float* __restrict__ Mt) {
  const int n = blockIdx.x, c = blockIdx.y;
  __shared__ float fvs[32];
  if (threadIdx.x < 32) fvs[threadIdx.x] = (threadIdx.x<25)? fv[n*25+threadIdx.x] : 0.f;
  __syncthreads();
  const float* yb = y + ((size_t)n*64+c)*TV_;
  float* mb = Mt + ((size_t)n*64+c)*T_;
  const int v = threadIdx.x & 31;
  const int grp = threadIdx.x >> 5;
  float fvv = fvs[v];
  for (int t = grp; t < 512; t += 8) {
    float val = (v<25) ? yb[t*25+v]*fvv : 0.f;
    for (int off=16; off; off>>=1) val += __shfl_down(val, off, 32);
    if (v==0) mb[t] = val * (1.f/25.f);
  }
}

// ---------------- k_tconv ----------------
__global__ void k_tconv(const float* __restrict__ Mt, const float* __restrict__ taw,
                        const float* __restrict__ tab, float* __restrict__ ft) {
  const int n = blockIdx.x;
  __shared__ float w[64*9];
  for (int e = threadIdx.x; e < 576; e += 256) w[e] = taw[e];
  __syncthreads();
  for (int t = threadIdx.x; t < 512; t += 256) {
    float acc = tab[0];
    for (int c = 0; c < 64; ++c) {
      const float* mrow = Mt + ((size_t)n*64+c)*512;
      #pragma unroll
      for (int k = 0; k < 9; ++k) {
        int tt = t + k - 4;
        if (tt >= 0 && tt < 512) acc += w[c*9+k]*mrow[tt];
      }
    }
    ft[n*512+t] = 1.f + 1.f/(1.f+expf(-acc));
  }
}

// ---------------- k_chan ----------------
__global__ void k_chan(const float* __restrict__ Mt, const float* __restrict__ ft,
    const float* __restrict__ f1w, const float* __restrict__ f1b,
    const float* __restrict__ f2w, const float* __restrict__ f2b,
    float* __restrict__ fc) {
  const int n = blockIdx.x;
  const int c = threadIdx.x;
  __shared__ float m3[64], h[32];
  float acc = 0.f;
  const float* mrow = Mt + ((size_t)n*64+c)*512;
  const float* fr = ft + n*512;
  for (int t = 0; t < 512; ++t) acc += mrow[t]*fr[t];
  m3[c] = acc * (1.f/512.f);
  __syncthreads();
  if (c < 32) {
    float a = f1b[c];
    for (int j = 0; j < 64; ++j) a += f1w[c*64+j]*m3[j];
    h[c] = fmaxf(a, 0.f);
  }
  __syncthreads();
  float a = f2b[c];
  for (int j = 0; j < 32; ++j) a += f2w[c*32+j]*h[j];
  fc[n*64+c] = 1.f + 1.f/(1.f+expf(-a));
}

// ---------------- k_tcnm: MFMA bf16 TCN (R2 geometry: 256-j tile) ----------------
#define BROW 456
#define BSTR 72        // bf16 units; conflict-free for b128 writes and frag reads
__global__ __launch_bounds__(256) void k_tcnm(
    const float* __restrict__ y, const float* __restrict__ fv,
    const float* __restrict__ ft, const float* __restrict__ fc,
    const ushort* __restrict__ Apack, float* __restrict__ out,
    float* __restrict__ tbns, float* __restrict__ tbnq) {
  const int jt = blockIdx.x, n = blockIdx.y;
  const int j0 = jt*256;
  const int tid = threadIdx.x;
  const int lane = tid & 63, wv = tid >> 6;
  __shared__ __align__(16) ushort Bs[BROW*BSTR];   // 65664 B
  __shared__ float fts[512], fvs[32], fcs[64];
  for (int e = tid; e < 512; e += 256) fts[e] = ft[n*512+e];
  if (tid < 32) fvs[tid] = (tid < 25) ? fv[n*25+tid] : 0.f;
  if (tid >= 64 && tid < 128) fcs[tid-64] = fc[n*64 + tid-64];
  __syncthreads();
  const float* yb = y + (size_t)n*64*TV_;
  for (int item = wv; item < 64; item += 4) {     // item = jc*8 + ce
    int jc = item >> 3, ce = item & 7;
    int j = jc*64 + lane;
    if (j < BROW) {
      int jg = j0 - 100 + j;
      unsigned p0=0,p1=0,p2=0,p3=0;
      if (jg >= 0 && jg < TV_) {
        int t = jg / 25, v = jg - t*25;
        float f = fts[t]*fvs[v];
        ushort pk[8];
        #pragma unroll
        for (int r = 0; r < 8; ++r) {
          int c = ce*8 + r;
          pk[r] = f2bf_rne(yb[(size_t)c*TV_ + jg] * f * fcs[c]);
        }
        p0 = (unsigned)pk[0] | ((unsigned)pk[1]<<16);
        p1 = (unsigned)pk[2] | ((unsigned)pk[3]<<16);
        p2 = (unsigned)pk[4] | ((unsigned)pk[5]<<16);
        p3 = (unsigned)pk[6] | ((unsigned)pk[7]<<16);
      }
      uint4 w4; w4.x=p0; w4.y=p1; w4.z=p2; w4.w=p3;
      *(uint4*)&Bs[j*BSTR + ce*8] = w4;
    }
  }
  __syncthreads();
  const int l15 = lane & 15, l4 = lane >> 4;
  f32x4 acc[16];
  #pragma unroll
  for (int i = 0; i < 16; ++i) acc[i] = (f32x4){0.f,0.f,0.f,0.f};
  for (int kk = 0; kk < 9; ++kk) {
    #pragma unroll
    for (int cb = 0; cb < 2; ++cb) {
      const int chunk = kk*2 + cb;
      bf16x8 afrag = *(const bf16x8*)(Apack + (size_t)((chunk*4 + wv)*64 + lane)*8);
      const int rbase = kk*25 + l15;
      const int ccol = cb*32 + l4*8;
      #pragma unroll
      for (int jt2 = 0; jt2 < 16; ++jt2) {
        bf16x8 bfrag = *(const bf16x8*)&Bs[(rbase + jt2*16)*BSTR + ccol];
        acc[jt2] = __builtin_amdgcn_mfma_f32_16x16x32_bf16(afrag, bfrag, acc[jt2], 0, 0, 0);
      }
    }
  }
  float so[4] = {0,0,0,0}, qo[4] = {0,0,0,0};
  const int obase = wv*16 + l4*4;
  #pragma unroll
  for (int jt2 = 0; jt2 < 16; ++jt2) {
    const int j = j0 + jt2*16 + l15;
    #pragma unroll
    for (int r = 0; r < 4; ++r) {
      float val = acc[jt2][r];
      out[((size_t)n*64 + obase + r)*TV_ + j] = val;
      so[r] += val; qo[r] += val*val;
    }
  }
  #pragma unroll
  for (int off = 1; off < 16; off <<= 1) {
    #pragma unroll
    for (int r = 0; r < 4; ++r) {
      so[r] += __shfl_xor(so[r], off);
      qo[r] += __shfl_xor(qo[r], off);
    }
  }
  if (l15 == 0) {
    #pragma unroll
    for (int r = 0; r < 4; ++r) {
      atomicAdd(&tbns[obase + r], so[r]);
      atomicAdd(&tbnq[obase + r], qo[r]);
    }
  }
}

// ---------------- k_final ----------------
__global__ void k_final(float* __restrict__ z, const float* __restrict__ x,
    const float* __restrict__ tbns, const float* __restrict__ tbnq,
    const float* __restrict__ tg, const float* __restrict__ tb) {
  size_t e = (size_t)blockIdx.x*256 + threadIdx.x;
  if (e < NCTV_/4) {
    int c = (int)((e / 3200) & 63);
    const float cnt = 1.f/819200.f;
    float m = tbns[c]*cnt;
    float var = tbnq[c]*cnt - m*m;
    float sc = tg[c]*rsqrtf(var+1e-5f);
    float sh = tb[c] - m*sc;
    float4 zv = ((float4*)z)[e];
    float4 xv = ((const float4*)x)[e];
    float4 o;
    o.x = fmaxf(sc*zv.x+sh+xv.x, 0.f);
    o.y = fmaxf(sc*zv.y+sh+xv.y, 0.f);
    o.z = fmaxf(sc*zv.z+sh+xv.z, 0.f);
    o.w = fmaxf(sc*zv.w+sh+xv.w, 0.f);
    ((float4*)z)[e] = o;
  }
}

extern "C" void kernel_launch(void* const* d_in, const int* in_sizes, int n_in,
                              void* d_out, int out_size, void* d_ws, size_t ws_size,
                              hipStream_t stream) {
  (void)in_sizes; (void)n_in; (void)out_size; (void)ws_size;
  const float* x    = (const float*)d_in[0];
  const float* PA   = (const float*)d_in[1];
  const float* alpha= (const float*)d_in[2];
  const float* Wa   = (const float*)d_in[3];
  const float* ba   = (const float*)d_in[4];
  const float* Wb   = (const float*)d_in[5];
  const float* bb   = (const float*)d_in[6];
  const float* Wd   = (const float*)d_in[7];
  // d_in[8] = bd : cancels exactly in training-mode BN1
  const float* bng  = (const float*)d_in[9];
  const float* bnb  = (const float*)d_in[10];
  const float* saw  = (const float*)d_in[11];
  const float* sab  = (const float*)d_in[12];
  const float* taw  = (const float*)d_in[13];
  const float* tab  = (const float*)d_in[14];
  const float* f1w  = (const float*)d_in[15];
  const float* f1b  = (const float*)d_in[16];
  const float* f2w  = (const float*)d_in[17];
  const float* f2b  = (const float*)d_in[18];
  const float* tcnw = (const float*)d_in[19];
  // d_in[20] = tcn_b : cancels exactly in training-mode BN2
  const float* tbg  = (const float*)d_in[21];
  const float* tbb  = (const float*)d_in[22];

  float* ws = (float*)d_ws;
  float* out = (float*)d_out;
  float* y    = ws + WS_Y;
  float* Mt   = ws + WS_MT;
  float* Araw = ws + WS_ARAW;
  float* Aeff = ws + WS_AEFF;
  float* Ms   = ws + WS_MS;
  float* fv   = ws + WS_FV;
  float* ft   = ws + WS_FT;
  float* fc   = ws + WS_FC;
  float* bns  = ws + WS_BNS;
  float* bnq  = ws + WS_BNQ;
  float* tbns = ws + WS_TBNS;
  float* tbnq = ws + WS_TBNQ;
  ushort* Apack = (ushort*)(ws + WS_WT);
  // Wd hi/lo packs live in the Araw region (dead after k_finishA; rewritten every iteration)
  ushort* Wdh = (ushort*)(ws + WS_ARAW);
  ushort* Wdl = Wdh + 12288;
  // Aeff fragment pack lives in the Mt region (dead until k_tmean writes it)
  ushort* Fpk = (ushort*)(ws + WS_MT);

  hipMemsetAsync(Araw, 0, 120000*sizeof(float), stream);
  hipMemsetAsync(bns, 0, 256*sizeof(float), stream);   // bns,bnq,tbns,tbnq contiguous

  k_prepA<<<144, 256, 0, stream>>>(tcnw, Apack);
  k_gramm<<<dim3(16,64), 256, 0, stream>>>(x, Wa, ba, Wb, bb, Araw);
  k_finishA<<<469, 256, 0, stream>>>(Araw, PA, alpha, Aeff);
  k_prepW<<<48, 256, 0, stream>>>(Wd, Wdh, Wdl);       // overwrites Araw (now dead)
  k_prepF<<<768, 256, 0, stream>>>(Aeff, Fpk);         // pack Aeff B-fragments (hi/lo)
  k_gcnm<<<dim3(52,64), 256, 0, stream>>>(x, Fpk, Wdh, Wdl, y, bns, bnq);
  k_bnapply<<<dim3(64,64), 256, 0, stream>>>(y, x, bns, bnq, bng, bnb, Ms);
  k_spat<<<64, 64, 0, stream>>>(Ms, saw, sab, fv);
  k_tmean<<<dim3(64,64), 256, 0, stream>>>(y, fv, Mt);
  k_tconv<<<64, 256, 0, stream>>>(Mt, taw, tab, ft);
  k_chan<<<64, 64, 0, stream>>>(Mt, ft, f1w, f1b, f2w, f2b, fc);
  k_tcnm<<<dim3(50,64), 256, 0, stream>>>(y, fv, ft, fc, Apack, out, tbns, tbnq);
  k_final<<<51200, 256, 0, stream>>>(out, x, tbns, tbnq, tbg, tbb);
}